// Round 23
// baseline (315.693 us; speedup 1.0000x reference)
//
#include <hip/hip_runtime.h>
#include <hip/hip_fp8.h>
#include <math.h>

#define B_SZ 512
#define C_SZ 100000
#define D_SZ 512

#define BN 64
#define NT64 1564           // ceil(100000/64) padded to even
#define NBLK (NT64 * 2)     // 3128 (divisible by 8)
#define KSTEPS 8            // 512 / 64
#define DEPTH 3

typedef __attribute__((ext_vector_type(4))) float f32x4;
typedef __attribute__((ext_vector_type(16))) float f32x16;
typedef __attribute__((ext_vector_type(4))) int i32x4;
typedef __attribute__((ext_vector_type(8))) int i32x8;

#define UNITY_SCALE 0x7F7F7F7F   // e8m0 127 = 2^0 in all byte slots

__device__ __forceinline__ void gload_lds16(const void* gptr, void* lptr) {
  __builtin_amdgcn_global_load_lds(
      (const __attribute__((address_space(1))) void*)gptr,
      (__attribute__((address_space(3))) void*)lptr,
      16, 0, 0);
}

__device__ __forceinline__ unsigned char f2fp8(float x) {
  __hip_fp8_e4m3 h(x);
  return (unsigned char)h.__x;
}
__device__ __forceinline__ float fp82f(unsigned int u) {
  __hip_fp8_e4m3 h;
  h.__x = (unsigned char)u;
  return (float)h;
}
__device__ __forceinline__ unsigned int pack4f8(float a, float b, float c, float d) {
  return (unsigned int)f2fp8(a) | ((unsigned int)f2fp8(b) << 8) |
         ((unsigned int)f2fp8(c) << 16) | ((unsigned int)f2fp8(d) << 24);
}

// Load one 32x32x64 fp8 operand fragment from fragment-ordered memory.
__device__ __forceinline__ i32x8 ld_frag(const unsigned char* base, int frag, int l) {
  i32x4 lo = *(const i32x4*)(base + frag * 2048 + l * 16);
  i32x4 hg = *(const i32x4*)(base + frag * 2048 + 1024 + l * 16);
  return __builtin_shufflevector(lo, hg, 0, 1, 2, 3, 4, 5, 6, 7);
}
__device__ __forceinline__ i32x8 ld_a(const unsigned char* p) {
  i32x4 lo = *(const i32x4*)(p);
  i32x4 hg = *(const i32x4*)(p + 1024);
  return __builtin_shufflevector(lo, hg, 0, 1, 2, 3, 4, 5, 6, 7);
}

// ---------------- kernel 1: normalize weight rows -> fp8 ----------------
__global__ __launch_bounds__(256) void k_norm_w(const float* __restrict__ w,
                                                unsigned char* __restrict__ w8) {
  const int row = blockIdx.x * 4 + (threadIdx.x >> 6);
  const int lane = threadIdx.x & 63;
  const float4* wr = (const float4*)(w + (size_t)row * D_SZ);
  float4 v0 = wr[lane];
  float4 v1 = wr[64 + lane];
  float ss = v0.x*v0.x + v0.y*v0.y + v0.z*v0.z + v0.w*v0.w
           + v1.x*v1.x + v1.y*v1.y + v1.z*v1.z + v1.w*v1.w;
  #pragma unroll
  for (int o = 32; o; o >>= 1) ss += __shfl_xor(ss, o, 64);
  const float rn = __builtin_amdgcn_rsqf(fmaxf(ss, 1e-24f));
  unsigned int* out = (unsigned int*)(w8 + (size_t)row * D_SZ);
  out[lane] = pack4f8(v0.x * rn, v0.y * rn, v0.z * rn, v0.w * rn);
  out[64 + lane] = pack4f8(v1.x * rn, v1.y * rn, v1.z * rn, v1.w * rn);
}

// ------- kernel 2: normalize embeddings, gather w_y, build fragment-ordered A --
// A8f layout: [frag 0..31][kstep 0..7][slot 0..127][16B].
// slot s holds row (frag*32 + (s&31)), source k-bytes
//   kstep*64 + ((s>>5)&1)*32 + ((s>>6)&1)*16 .. +16.
// Row 2b = fp8(e_hat[b]); row 2b+1 = fp8 w_hat[label[b]].
__global__ __launch_bounds__(64) void k_prep(const float* __restrict__ e,
                                             const int* __restrict__ labels,
                                             const unsigned char* __restrict__ w8,
                                             unsigned char* __restrict__ A8f,
                                             float4* __restrict__ params) {
  const int b = blockIdx.x;
  const int lane = threadIdx.x;
  const float4* er = (const float4*)(e + (size_t)b * D_SZ);
  float4 v0 = er[lane], v1 = er[64 + lane];
  float ss = v0.x*v0.x + v0.y*v0.y + v0.z*v0.z + v0.w*v0.w
           + v1.x*v1.x + v1.y*v1.y + v1.z*v1.z + v1.w*v1.w;
  #pragma unroll
  for (int o = 32; o; o >>= 1) ss += __shfl_xor(ss, o, 64);
  const float rn = __builtin_amdgcn_rsqf(fmaxf(ss, 1e-24f));
  v0.x *= rn; v0.y *= rn; v0.z *= rn; v0.w *= rn;
  v1.x *= rn; v1.y *= rn; v1.z *= rn; v1.w *= rn;

  const unsigned int ue0 = pack4f8(v0.x, v0.y, v0.z, v0.w);   // elems 4l..
  const unsigned int ue1 = pack4f8(v1.x, v1.y, v1.z, v1.w);   // elems 256+4l..

  const int lab = labels[b];
  const unsigned int* wr = (const unsigned int*)(w8 + (size_t)lab * D_SZ);
  const unsigned int w0 = wr[lane], w1 = wr[64 + lane];

  const int re = 2 * b;
  const int frag = re >> 5;
  const int rife = re & 31;            // e row within frag; w_y row = rife+1
  const int wk = (4 * lane) & 63;
  const int ks = lane >> 4;            // (4*lane)>>6
  const int sbits = (((wk >> 5) & 1) << 5) | (((wk >> 4) & 1) << 6);
  const int byteo = wk & 15;
  unsigned char* fb = A8f + (size_t)frag * 16384;
  unsigned char* pe = fb + (rife | sbits) * 16 + byteo;
  unsigned char* pw = fb + ((rife + 1) | sbits) * 16 + byteo;
  *(unsigned int*)(pe + ks * 2048) = ue0;
  *(unsigned int*)(pe + (ks + 4) * 2048) = ue1;
  *(unsigned int*)(pw + ks * 2048) = w0;
  *(unsigned int*)(pw + (ks + 4) * 2048) = w1;

  float d = v0.x * fp82f(w0 & 255) + v0.y * fp82f((w0 >> 8) & 255)
          + v0.z * fp82f((w0 >> 16) & 255) + v0.w * fp82f(w0 >> 24)
          + v1.x * fp82f(w1 & 255) + v1.y * fp82f((w1 >> 8) & 255)
          + v1.z * fp82f((w1 >> 16) & 255) + v1.w * fp82f(w1 >> 24);
  #pragma unroll
  for (int o = 32; o; o >>= 1) d += __shfl_xor(d, o, 64);

  if (lane == 0) {
    const float cos_m = 0.877582561890372716f;  // cos(0.5)
    const float sin_m = 0.479425538604203000f;  // sin(0.5)
    float cos_t = fminf(fmaxf(d, -1.0f), 1.0f);
    float sin_t = sqrtf(fmaxf(1.0f - cos_t * cos_t, 0.0f));
    float cos_tm = cos_t * cos_m - sin_t * sin_m;
    float sin_tm = sin_t * cos_m + cos_t * sin_m;
    float inv_st = 1.0f / fmaxf(sin_t, 1e-20f);
    params[b] = make_float4(cos_tm, sin_m * inv_st, sin_tm * inv_st, 0.0f);
  }
}

// -- kernel 3: big-tile low-occupancy. 256 thr (4 waves), wave = 4m x 2n  --
// -- 32x32 tiles (8 acc, ~195 regs at (256,2) cap 256). A direct from L2; --
// -- B (64 x 64) DEPTH-3 counted-vmcnt. No ered/atomics: waves own rows.  --
__device__ __forceinline__ float termf(float de, float dwy, float4 p, bool kill) {
  float c = fminf(fmaxf(de, -1.0f), 1.0f);
  float s = p.z * dwy - p.y * de;            // (sin_tm*dwy - sin_m*de)/sin_t
  float x = fmaxf(fmaf(-2.0f, s, 2.0f), 1e-20f);
  float t = (c - p.x) * __builtin_amdgcn_rsqf(x);
  float r = __expf(t);
  return kill ? 0.0f : r;
}

__global__ __launch_bounds__(256, 2) void k_gemm(const unsigned char* __restrict__ A8f,
                                                 const unsigned char* __restrict__ W8,
                                                 const float4* __restrict__ params,
                                                 const int* __restrict__ labels,
                                                 float* __restrict__ part) {
  // B LDS: frag f (32 rows x 64 k = 2 KB) at f*2048; 2 frags = 4 KB/buffer.
  __shared__ __align__(32) unsigned char Bt[DEPTH][BN * 64];   // 3 x 4 KB

  const int bid = blockIdx.x;
  const int p = (bid & 7) * (NBLK / 8) + (bid >> 3);  // XCD-chunked remap
  const int nt = p >> 1, mhalf = p & 1;               // mhalf fastest
  const int t = threadIdx.x;
  const int w = t >> 6, l = t & 63;                    // 4 waves
  const int n0 = nt * BN;

  // B staging: thread t stages slot t (16 B); 256 slots = 2 frags.
  const int kpart = ((t >> 5) & 1) * 32 + ((t >> 6) & 1) * 16;
  int brow_s = n0 + (t >> 7) * 32 + (t & 31);
  if (brow_s >= C_SZ) brow_s = C_SZ - 1;   // clamp; masked in epilogue
  const int boffs = brow_s * D_SZ + kpart;

  // A: fragment-ordered global, L2-resident. Wave's m-frags: mhalf*16 + w*4 + mf.
  const unsigned char* afb =
      A8f + (size_t)(mhalf * 16 + w * 4) * 16384 + l * 16;

  f32x16 c00 = {}, c01 = {}, c10 = {}, c11 = {};
  f32x16 c20 = {}, c21 = {}, c30 = {}, c31 = {};
  const int hi = l >> 5;
  const int col = l & 31;

#define STAGE(d, ts)                                                        \
  gload_lds16(W8 + (size_t)(boffs + (ts) * 64), (void*)(Bt[d] + t * 16))

  // ---- prologue: stage B tiles 0,1,2 ----
  STAGE(0, 0);
  STAGE(1, 1);
  STAGE(2, 2);
  asm volatile("s_waitcnt vmcnt(2) lgkmcnt(0)" ::: "memory");  // tile 0 landed
  __builtin_amdgcn_s_barrier();

  // ---- main loop: compute(s); vmcnt(1); barrier; stage(s+3) ----
  #pragma unroll
  for (int s = 0; s < KSTEPS; ++s) {
    const int d = s % DEPTH;
    i32x8 av0 = ld_a(afb + 0 * 16384 + s * 2048);
    i32x8 av1 = ld_a(afb + 1 * 16384 + s * 2048);
    i32x8 av2 = ld_a(afb + 2 * 16384 + s * 2048);
    i32x8 av3 = ld_a(afb + 3 * 16384 + s * 2048);
    i32x8 bv = ld_frag(Bt[d], 0, l);
    __builtin_amdgcn_s_setprio(1);
    c00 = __builtin_amdgcn_mfma_scale_f32_32x32x64_f8f6f4(
        av0, bv, c00, 0, 0, 0, UNITY_SCALE, 0, UNITY_SCALE);
    c10 = __builtin_amdgcn_mfma_scale_f32_32x32x64_f8f6f4(
        av1, bv, c10, 0, 0, 0, UNITY_SCALE, 0, UNITY_SCALE);
    c20 = __builtin_amdgcn_mfma_scale_f32_32x32x64_f8f6f4(
        av2, bv, c20, 0, 0, 0, UNITY_SCALE, 0, UNITY_SCALE);
    c30 = __builtin_amdgcn_mfma_scale_f32_32x32x64_f8f6f4(
        av3, bv, c30, 0, 0, 0, UNITY_SCALE, 0, UNITY_SCALE);
    __builtin_amdgcn_s_setprio(0);
    bv = ld_frag(Bt[d], 1, l);           // reuse bv regs to cap live set
    __builtin_amdgcn_s_setprio(1);
    c01 = __builtin_amdgcn_mfma_scale_f32_32x32x64_f8f6f4(
        av0, bv, c01, 0, 0, 0, UNITY_SCALE, 0, UNITY_SCALE);
    c11 = __builtin_amdgcn_mfma_scale_f32_32x32x64_f8f6f4(
        av1, bv, c11, 0, 0, 0, UNITY_SCALE, 0, UNITY_SCALE);
    c21 = __builtin_amdgcn_mfma_scale_f32_32x32x64_f8f6f4(
        av2, bv, c21, 0, 0, 0, UNITY_SCALE, 0, UNITY_SCALE);
    c31 = __builtin_amdgcn_mfma_scale_f32_32x32x64_f8f6f4(
        av3, bv, c31, 0, 0, 0, UNITY_SCALE, 0, UNITY_SCALE);
    __builtin_amdgcn_s_setprio(0);
    if (s < KSTEPS - 1) {
      if (s < KSTEPS - 2)
        asm volatile("s_waitcnt vmcnt(1)" ::: "memory");   // tile s+1 landed
      else
        asm volatile("s_waitcnt vmcnt(0)" ::: "memory");   // last: drain
      __builtin_amdgcn_s_barrier();   // all waves done reading buf d
      if (s + 3 < KSTEPS)
        STAGE(d, s + 3);
    }
  }
#undef STAGE

  // Epilogue. 32x32 C/D: col = lane&31, row = (r&3)+8*(r>>2)+4*hi.
  // Interleaved A rows: even row = dot_e, odd = dot_wy -> reg pair (r, r+1).
  // Wave exclusively owns its batch rows -> direct stores, no atomics.
#define EPI(CM0, CM1, MF)                                                   \
  do {                                                                      \
    _Pragma("unroll")                                                       \
    for (int rp = 0; rp < 8; ++rp) {                                        \
      const int r = 2 * rp;                                                 \
      const int rowk = (rp & 1) + 4 * (rp >> 1) + 2 * hi;                   \
      const int gb = (mhalf * 16 + w * 4 + (MF)) * 16 + rowk;               \
      float4 pp = params[gb];                                               \
      int lab = labels[gb];                                                 \
      int j0 = n0 + col, j1 = j0 + 32;                                      \
      float sv = termf(CM0[r], CM0[r + 1], pp, (j0 >= C_SZ) || (j0 == lab)) \
               + termf(CM1[r], CM1[r + 1], pp, (j1 >= C_SZ) || (j1 == lab));\
      _Pragma("unroll")                                                     \
      for (int o = 1; o < 32; o <<= 1) sv += __shfl_xor(sv, o, 64);         \
      if (col == 0) part[(size_t)gb * NT64 + nt] = sv;                      \
    }                                                                       \
  } while (0)

  EPI(c00, c01, 0);
  EPI(c10, c11, 1);
  EPI(c20, c21, 2);
  EPI(c30, c31, 3);
#undef EPI
}

// ---------------- kernel 4a: per-batch row sum + log1p ----------------
__global__ __launch_bounds__(256) void k_rowsum(const float* __restrict__ part,
                                                float* __restrict__ rowsum) {
  const int b = blockIdx.x;
  float s = 0.0f;
  for (int i = threadIdx.x; i < NT64; i += 256) s += part[(size_t)b * NT64 + i];
  #pragma unroll
  for (int o = 32; o; o >>= 1) s += __shfl_xor(s, o, 64);
  __shared__ float red[4];
  if ((threadIdx.x & 63) == 0) red[threadIdx.x >> 6] = s;
  __syncthreads();
  if (threadIdx.x == 0)
    rowsum[b] = log1pf(red[0] + red[1] + red[2] + red[3]);
}

// ---------------- kernel 4b: final mean ----------------
__global__ __launch_bounds__(512) void k_final(const float* __restrict__ rowsum,
                                               float* __restrict__ out) {
  const int b = threadIdx.x;
  float v = rowsum[b];
  __shared__ float red[512];
  red[b] = v;
  __syncthreads();
  #pragma unroll
  for (int o = 256; o; o >>= 1) {
    if (b < o) red[b] += red[b + o];
    __syncthreads();
  }
  if (b == 0) out[0] = red[0] / (float)B_SZ;
}

extern "C" void kernel_launch(void* const* d_in, const int* in_sizes, int n_in,
                              void* d_out, int out_size, void* d_ws, size_t ws_size,
                              hipStream_t stream) {
  const float* emb = (const float*)d_in[0];
  const int* labels = (const int*)d_in[1];
  const float* w = (const float*)d_in[2];

  char* ws = (char*)d_ws;
  unsigned char* w8 = (unsigned char*)ws;                  // 100000*512 B
  size_t off = (size_t)C_SZ * D_SZ;
  unsigned char* A8f = (unsigned char*)(ws + off);         // 32*16384 = 512 KB
  off += (size_t)2 * B_SZ * D_SZ;
  float4* params = (float4*)(ws + off);                    // 512*16 B
  off += (size_t)B_SZ * 16;
  float* part = (float*)(ws + off);                        // 512*1564*4 B
  off += (size_t)B_SZ * NT64 * 4;
  float* rowsum = (float*)(ws + off);                      // 512*4 B
  off += (size_t)B_SZ * 4;

  k_norm_w<<<dim3(C_SZ / 4), dim3(256), 0, stream>>>(w, w8);
  k_prep<<<dim3(B_SZ), dim3(64), 0, stream>>>(emb, labels, w8, A8f, params);
  k_gemm<<<dim3(NBLK), dim3(256), 0, stream>>>(A8f, w8, params, labels, part);
  k_rowsum<<<dim3(B_SZ), dim3(256), 0, stream>>>(part, rowsum);
  k_final<<<dim3(1), dim3(512), 0, stream>>>(rowsum, (float*)d_out);
}

// Round 24
// 254.900 us; speedup vs baseline: 1.2385x; 1.2385x over previous
//
#include <hip/hip_runtime.h>
#include <hip/hip_fp8.h>
#include <math.h>

#define B_SZ 512
#define C_SZ 100000
#define D_SZ 512

#define BN 64
#define NT64 1564           // ceil(100000/64) padded to even
#define NBLK (NT64 * 2)     // 3128 (divisible by 8)
#define KSTEPS 8            // 512 / 64
#define DEPTH 3

typedef __attribute__((ext_vector_type(4))) float f32x4;
typedef __attribute__((ext_vector_type(16))) float f32x16;
typedef __attribute__((ext_vector_type(4))) int i32x4;
typedef __attribute__((ext_vector_type(8))) int i32x8;

#define UNITY_SCALE 0x7F7F7F7F   // e8m0 127 = 2^0 in all byte slots

__device__ __forceinline__ void gload_lds16(const void* gptr, void* lptr) {
  __builtin_amdgcn_global_load_lds(
      (const __attribute__((address_space(1))) void*)gptr,
      (__attribute__((address_space(3))) void*)lptr,
      16, 0, 0);
}

__device__ __forceinline__ unsigned char f2fp8(float x) {
  __hip_fp8_e4m3 h(x);
  return (unsigned char)h.__x;
}
__device__ __forceinline__ float fp82f(unsigned int u) {
  __hip_fp8_e4m3 h;
  h.__x = (unsigned char)u;
  return (float)h;
}
__device__ __forceinline__ unsigned int pack4f8(float a, float b, float c, float d) {
  return (unsigned int)f2fp8(a) | ((unsigned int)f2fp8(b) << 8) |
         ((unsigned int)f2fp8(c) << 16) | ((unsigned int)f2fp8(d) << 24);
}

// Load one 32x32x64 fp8 operand fragment from fragment-ordered memory.
__device__ __forceinline__ i32x8 ld_frag(const unsigned char* base, int frag, int l) {
  i32x4 lo = *(const i32x4*)(base + frag * 2048 + l * 16);
  i32x4 hg = *(const i32x4*)(base + frag * 2048 + 1024 + l * 16);
  return __builtin_shufflevector(lo, hg, 0, 1, 2, 3, 4, 5, 6, 7);
}
__device__ __forceinline__ i32x8 ld_a(const unsigned char* p) {
  i32x4 lo = *(const i32x4*)(p);
  i32x4 hg = *(const i32x4*)(p + 1024);
  return __builtin_shufflevector(lo, hg, 0, 1, 2, 3, 4, 5, 6, 7);
}

// ---------------- kernel 1: normalize weight rows -> fp8 ----------------
__global__ __launch_bounds__(256) void k_norm_w(const float* __restrict__ w,
                                                unsigned char* __restrict__ w8) {
  const int row = blockIdx.x * 4 + (threadIdx.x >> 6);
  const int lane = threadIdx.x & 63;
  const float4* wr = (const float4*)(w + (size_t)row * D_SZ);
  float4 v0 = wr[lane];
  float4 v1 = wr[64 + lane];
  float ss = v0.x*v0.x + v0.y*v0.y + v0.z*v0.z + v0.w*v0.w
           + v1.x*v1.x + v1.y*v1.y + v1.z*v1.z + v1.w*v1.w;
  #pragma unroll
  for (int o = 32; o; o >>= 1) ss += __shfl_xor(ss, o, 64);
  const float rn = __builtin_amdgcn_rsqf(fmaxf(ss, 1e-24f));
  unsigned int* out = (unsigned int*)(w8 + (size_t)row * D_SZ);
  out[lane] = pack4f8(v0.x * rn, v0.y * rn, v0.z * rn, v0.w * rn);
  out[64 + lane] = pack4f8(v1.x * rn, v1.y * rn, v1.z * rn, v1.w * rn);
}

// ------- kernel 2: normalize embeddings, gather w_y, build fragment-ordered A --
// A8f layout: [frag 0..31][kstep 0..7][slot 0..127][16B].
// slot s holds row (frag*32 + (s&31)), source k-bytes
//   kstep*64 + ((s>>5)&1)*32 + ((s>>6)&1)*16 .. +16.
// Row 2b = fp8(e_hat[b]); row 2b+1 = fp8 w_hat[label[b]].
__global__ __launch_bounds__(64) void k_prep(const float* __restrict__ e,
                                             const int* __restrict__ labels,
                                             const unsigned char* __restrict__ w8,
                                             unsigned char* __restrict__ A8f,
                                             float4* __restrict__ params) {
  const int b = blockIdx.x;
  const int lane = threadIdx.x;
  const float4* er = (const float4*)(e + (size_t)b * D_SZ);
  float4 v0 = er[lane], v1 = er[64 + lane];
  float ss = v0.x*v0.x + v0.y*v0.y + v0.z*v0.z + v0.w*v0.w
           + v1.x*v1.x + v1.y*v1.y + v1.z*v1.z + v1.w*v1.w;
  #pragma unroll
  for (int o = 32; o; o >>= 1) ss += __shfl_xor(ss, o, 64);
  const float rn = __builtin_amdgcn_rsqf(fmaxf(ss, 1e-24f));
  v0.x *= rn; v0.y *= rn; v0.z *= rn; v0.w *= rn;
  v1.x *= rn; v1.y *= rn; v1.z *= rn; v1.w *= rn;

  const unsigned int ue0 = pack4f8(v0.x, v0.y, v0.z, v0.w);   // elems 4l..
  const unsigned int ue1 = pack4f8(v1.x, v1.y, v1.z, v1.w);   // elems 256+4l..

  const int lab = labels[b];
  const unsigned int* wr = (const unsigned int*)(w8 + (size_t)lab * D_SZ);
  const unsigned int w0 = wr[lane], w1 = wr[64 + lane];

  const int re = 2 * b;
  const int frag = re >> 5;
  const int rife = re & 31;            // e row within frag; w_y row = rife+1
  const int wk = (4 * lane) & 63;
  const int ks = lane >> 4;            // (4*lane)>>6
  const int sbits = (((wk >> 5) & 1) << 5) | (((wk >> 4) & 1) << 6);
  const int byteo = wk & 15;
  unsigned char* fb = A8f + (size_t)frag * 16384;
  unsigned char* pe = fb + (rife | sbits) * 16 + byteo;
  unsigned char* pw = fb + ((rife + 1) | sbits) * 16 + byteo;
  *(unsigned int*)(pe + ks * 2048) = ue0;
  *(unsigned int*)(pe + (ks + 4) * 2048) = ue1;
  *(unsigned int*)(pw + ks * 2048) = w0;
  *(unsigned int*)(pw + (ks + 4) * 2048) = w1;

  float d = v0.x * fp82f(w0 & 255) + v0.y * fp82f((w0 >> 8) & 255)
          + v0.z * fp82f((w0 >> 16) & 255) + v0.w * fp82f(w0 >> 24)
          + v1.x * fp82f(w1 & 255) + v1.y * fp82f((w1 >> 8) & 255)
          + v1.z * fp82f((w1 >> 16) & 255) + v1.w * fp82f(w1 >> 24);
  #pragma unroll
  for (int o = 32; o; o >>= 1) d += __shfl_xor(d, o, 64);

  if (lane == 0) {
    const float cos_m = 0.877582561890372716f;  // cos(0.5)
    const float sin_m = 0.479425538604203000f;  // sin(0.5)
    float cos_t = fminf(fmaxf(d, -1.0f), 1.0f);
    float sin_t = sqrtf(fmaxf(1.0f - cos_t * cos_t, 0.0f));
    float cos_tm = cos_t * cos_m - sin_t * sin_m;
    float sin_tm = sin_t * cos_m + cos_t * sin_m;
    float inv_st = 1.0f / fmaxf(sin_t, 1e-20f);
    params[b] = make_float4(cos_tm, sin_m * inv_st, sin_tm * inv_st, 0.0f);
  }
}

// -- kernel 3: big-tile low-occupancy. 256 thr (4 waves), wave = 4m x 2n  --
// -- 32x32 tiles (8 acc = 128 AGPR) at (256,1) -> 512-reg ceiling, no     --
// -- spill. A direct from L2; B DEPTH-3 counted-vmcnt; direct part store. --
__device__ __forceinline__ float termf(float de, float dwy, float4 p, bool kill) {
  float c = fminf(fmaxf(de, -1.0f), 1.0f);
  float s = p.z * dwy - p.y * de;            // (sin_tm*dwy - sin_m*de)/sin_t
  float x = fmaxf(fmaf(-2.0f, s, 2.0f), 1e-20f);
  float t = (c - p.x) * __builtin_amdgcn_rsqf(x);
  float r = __expf(t);
  return kill ? 0.0f : r;
}

__global__ __launch_bounds__(256, 1) void k_gemm(const unsigned char* __restrict__ A8f,
                                                 const unsigned char* __restrict__ W8,
                                                 const float4* __restrict__ params,
                                                 const int* __restrict__ labels,
                                                 float* __restrict__ part) {
  // B LDS: frag f (32 rows x 64 k = 2 KB) at f*2048; 2 frags = 4 KB/buffer.
  __shared__ __align__(32) unsigned char Bt[DEPTH][BN * 64];   // 3 x 4 KB

  const int bid = blockIdx.x;
  const int p = (bid & 7) * (NBLK / 8) + (bid >> 3);  // XCD-chunked remap
  const int nt = p >> 1, mhalf = p & 1;               // mhalf fastest
  const int t = threadIdx.x;
  const int w = t >> 6, l = t & 63;                    // 4 waves
  const int n0 = nt * BN;

  // B staging: thread t stages slot t (16 B); 256 slots = 2 frags.
  const int kpart = ((t >> 5) & 1) * 32 + ((t >> 6) & 1) * 16;
  int brow_s = n0 + (t >> 7) * 32 + (t & 31);
  if (brow_s >= C_SZ) brow_s = C_SZ - 1;   // clamp; masked in epilogue
  const int boffs = brow_s * D_SZ + kpart;

  // A: fragment-ordered global, L2-resident. Wave's m-frags: mhalf*16 + w*4 + mf.
  const unsigned char* afb =
      A8f + (size_t)(mhalf * 16 + w * 4) * 16384 + l * 16;

  f32x16 c00 = {}, c01 = {}, c10 = {}, c11 = {};
  f32x16 c20 = {}, c21 = {}, c30 = {}, c31 = {};
  const int hi = l >> 5;
  const int col = l & 31;

#define STAGE(d, ts)                                                        \
  gload_lds16(W8 + (size_t)(boffs + (ts) * 64), (void*)(Bt[d] + t * 16))

  // ---- prologue: stage B tiles 0,1,2 ----
  STAGE(0, 0);
  STAGE(1, 1);
  STAGE(2, 2);
  asm volatile("s_waitcnt vmcnt(2) lgkmcnt(0)" ::: "memory");  // tile 0 landed
  __builtin_amdgcn_s_barrier();

  // ---- main loop: compute(s); vmcnt(1); barrier; stage(s+3) ----
  #pragma unroll
  for (int s = 0; s < KSTEPS; ++s) {
    const int d = s % DEPTH;
    i32x8 av0 = ld_a(afb + 0 * 16384 + s * 2048);
    i32x8 av1 = ld_a(afb + 1 * 16384 + s * 2048);
    i32x8 av2 = ld_a(afb + 2 * 16384 + s * 2048);
    i32x8 av3 = ld_a(afb + 3 * 16384 + s * 2048);
    i32x8 bv = ld_frag(Bt[d], 0, l);
    __builtin_amdgcn_s_setprio(1);
    c00 = __builtin_amdgcn_mfma_scale_f32_32x32x64_f8f6f4(
        av0, bv, c00, 0, 0, 0, UNITY_SCALE, 0, UNITY_SCALE);
    c10 = __builtin_amdgcn_mfma_scale_f32_32x32x64_f8f6f4(
        av1, bv, c10, 0, 0, 0, UNITY_SCALE, 0, UNITY_SCALE);
    c20 = __builtin_amdgcn_mfma_scale_f32_32x32x64_f8f6f4(
        av2, bv, c20, 0, 0, 0, UNITY_SCALE, 0, UNITY_SCALE);
    c30 = __builtin_amdgcn_mfma_scale_f32_32x32x64_f8f6f4(
        av3, bv, c30, 0, 0, 0, UNITY_SCALE, 0, UNITY_SCALE);
    __builtin_amdgcn_s_setprio(0);
    bv = ld_frag(Bt[d], 1, l);           // reuse bv regs to cap live set
    __builtin_amdgcn_s_setprio(1);
    c01 = __builtin_amdgcn_mfma_scale_f32_32x32x64_f8f6f4(
        av0, bv, c01, 0, 0, 0, UNITY_SCALE, 0, UNITY_SCALE);
    c11 = __builtin_amdgcn_mfma_scale_f32_32x32x64_f8f6f4(
        av1, bv, c11, 0, 0, 0, UNITY_SCALE, 0, UNITY_SCALE);
    c21 = __builtin_amdgcn_mfma_scale_f32_32x32x64_f8f6f4(
        av2, bv, c21, 0, 0, 0, UNITY_SCALE, 0, UNITY_SCALE);
    c31 = __builtin_amdgcn_mfma_scale_f32_32x32x64_f8f6f4(
        av3, bv, c31, 0, 0, 0, UNITY_SCALE, 0, UNITY_SCALE);
    __builtin_amdgcn_s_setprio(0);
    if (s < KSTEPS - 1) {
      if (s < KSTEPS - 2)
        asm volatile("s_waitcnt vmcnt(1)" ::: "memory");   // tile s+1 landed
      else
        asm volatile("s_waitcnt vmcnt(0)" ::: "memory");   // last: drain
      __builtin_amdgcn_s_barrier();   // all waves done reading buf d
      if (s + 3 < KSTEPS)
        STAGE(d, s + 3);
    }
  }
#undef STAGE

  // Epilogue. 32x32 C/D: col = lane&31, row = (r&3)+8*(r>>2)+4*hi.
  // Interleaved A rows: even row = dot_e, odd = dot_wy -> reg pair (r, r+1).
  // Wave exclusively owns its batch rows -> direct stores, no atomics.
#define EPI(CM0, CM1, MF)                                                   \
  do {                                                                      \
    _Pragma("unroll")                                                       \
    for (int rp = 0; rp < 8; ++rp) {                                        \
      const int r = 2 * rp;                                                 \
      const int rowk = (rp & 1) + 4 * (rp >> 1) + 2 * hi;                   \
      const int gb = (mhalf * 16 + w * 4 + (MF)) * 16 + rowk;               \
      float4 pp = params[gb];                                               \
      int lab = labels[gb];                                                 \
      int j0 = n0 + col, j1 = j0 + 32;                                      \
      float sv = termf(CM0[r], CM0[r + 1], pp, (j0 >= C_SZ) || (j0 == lab)) \
               + termf(CM1[r], CM1[r + 1], pp, (j1 >= C_SZ) || (j1 == lab));\
      _Pragma("unroll")                                                     \
      for (int o = 1; o < 32; o <<= 1) sv += __shfl_xor(sv, o, 64);         \
      if (col == 0) part[(size_t)gb * NT64 + nt] = sv;                      \
    }                                                                       \
  } while (0)

  EPI(c00, c01, 0);
  EPI(c10, c11, 1);
  EPI(c20, c21, 2);
  EPI(c30, c31, 3);
#undef EPI
}

// ---------------- kernel 4a: per-batch row sum + log1p ----------------
__global__ __launch_bounds__(256) void k_rowsum(const float* __restrict__ part,
                                                float* __restrict__ rowsum) {
  const int b = blockIdx.x;
  float s = 0.0f;
  for (int i = threadIdx.x; i < NT64; i += 256) s += part[(size_t)b * NT64 + i];
  #pragma unroll
  for (int o = 32; o; o >>= 1) s += __shfl_xor(s, o, 64);
  __shared__ float red[4];
  if ((threadIdx.x & 63) == 0) red[threadIdx.x >> 6] = s;
  __syncthreads();
  if (threadIdx.x == 0)
    rowsum[b] = log1pf(red[0] + red[1] + red[2] + red[3]);
}

// ---------------- kernel 4b: final mean ----------------
__global__ __launch_bounds__(512) void k_final(const float* __restrict__ rowsum,
                                               float* __restrict__ out) {
  const int b = threadIdx.x;
  float v = rowsum[b];
  __shared__ float red[512];
  red[b] = v;
  __syncthreads();
  #pragma unroll
  for (int o = 256; o; o >>= 1) {
    if (b < o) red[b] += red[b + o];
    __syncthreads();
  }
  if (b == 0) out[0] = red[0] / (float)B_SZ;
}

extern "C" void kernel_launch(void* const* d_in, const int* in_sizes, int n_in,
                              void* d_out, int out_size, void* d_ws, size_t ws_size,
                              hipStream_t stream) {
  const float* emb = (const float*)d_in[0];
  const int* labels = (const int*)d_in[1];
  const float* w = (const float*)d_in[2];

  char* ws = (char*)d_ws;
  unsigned char* w8 = (unsigned char*)ws;                  // 100000*512 B
  size_t off = (size_t)C_SZ * D_SZ;
  unsigned char* A8f = (unsigned char*)(ws + off);         // 32*16384 = 512 KB
  off += (size_t)2 * B_SZ * D_SZ;
  float4* params = (float4*)(ws + off);                    // 512*16 B
  off += (size_t)B_SZ * 16;
  float* part = (float*)(ws + off);                        // 512*1564*4 B
  off += (size_t)B_SZ * NT64 * 4;
  float* rowsum = (float*)(ws + off);                      // 512*4 B
  off += (size_t)B_SZ * 4;

  k_norm_w<<<dim3(C_SZ / 4), dim3(256), 0, stream>>>(w, w8);
  k_prep<<<dim3(B_SZ), dim3(64), 0, stream>>>(emb, labels, w8, A8f, params);
  k_gemm<<<dim3(NBLK), dim3(256), 0, stream>>>(A8f, w8, params, labels, part);
  k_rowsum<<<dim3(B_SZ), dim3(256), 0, stream>>>(part, rowsum);
  k_final<<<dim3(1), dim3(512), 0, stream>>>(rowsum, (float*)d_out);
}

// Round 25
// 135.413 us; speedup vs baseline: 2.3313x; 1.8824x over previous
//
#include <hip/hip_runtime.h>
#include <hip/hip_fp8.h>
#include <math.h>

#define B_SZ 512
#define C_SZ 100000
#define D_SZ 512

#define BN 128
#define NTILES 782          // ceil(100000/128)
#define MT 8                // 1024 A-rows / 128
#define NBLK (NTILES * MT)  // 6256 (divisible by 8)
#define KSTEPS 8            // 512 / 64
#define DEPTH 2

typedef __attribute__((ext_vector_type(4))) float f32x4;
typedef __attribute__((ext_vector_type(16))) float f32x16;
typedef __attribute__((ext_vector_type(4))) int i32x4;
typedef __attribute__((ext_vector_type(8))) int i32x8;

#define UNITY_SCALE 0x7F7F7F7F   // e8m0 127 = 2^0 in all byte slots

__device__ __forceinline__ void gload_lds16(const void* gptr, void* lptr) {
  __builtin_amdgcn_global_load_lds(
      (const __attribute__((address_space(1))) void*)gptr,
      (__attribute__((address_space(3))) void*)lptr,
      16, 0, 0);
}

__device__ __forceinline__ unsigned char f2fp8(float x) {
  __hip_fp8_e4m3 h(x);
  return (unsigned char)h.__x;
}
__device__ __forceinline__ float fp82f(unsigned int u) {
  __hip_fp8_e4m3 h;
  h.__x = (unsigned char)u;
  return (float)h;
}
__device__ __forceinline__ unsigned int pack4f8(float a, float b, float c, float d) {
  return (unsigned int)f2fp8(a) | ((unsigned int)f2fp8(b) << 8) |
         ((unsigned int)f2fp8(c) << 16) | ((unsigned int)f2fp8(d) << 24);
}

// Load one 32x32x64 fp8 B-operand fragment from fragment-ordered LDS.
__device__ __forceinline__ i32x8 ld_frag(const unsigned char* base, int frag, int l) {
  i32x4 lo = *(const i32x4*)(base + frag * 2048 + l * 16);
  i32x4 hg = *(const i32x4*)(base + frag * 2048 + 1024 + l * 16);
  return __builtin_shufflevector(lo, hg, 0, 1, 2, 3, 4, 5, 6, 7);
}
__device__ __forceinline__ i32x8 ld_a(const unsigned char* p) {
  i32x4 lo = *(const i32x4*)(p);
  i32x4 hg = *(const i32x4*)(p + 1024);
  return __builtin_shufflevector(lo, hg, 0, 1, 2, 3, 4, 5, 6, 7);
}

// ---------------- kernel 1: normalize weight rows -> fp8 ----------------
__global__ __launch_bounds__(256) void k_norm_w(const float* __restrict__ w,
                                                unsigned char* __restrict__ w8) {
  const int row = blockIdx.x * 4 + (threadIdx.x >> 6);
  const int lane = threadIdx.x & 63;
  const float4* wr = (const float4*)(w + (size_t)row * D_SZ);
  float4 v0 = wr[lane];
  float4 v1 = wr[64 + lane];
  float ss = v0.x*v0.x + v0.y*v0.y + v0.z*v0.z + v0.w*v0.w
           + v1.x*v1.x + v1.y*v1.y + v1.z*v1.z + v1.w*v1.w;
  #pragma unroll
  for (int o = 32; o; o >>= 1) ss += __shfl_xor(ss, o, 64);
  const float rn = __builtin_amdgcn_rsqf(fmaxf(ss, 1e-24f));
  unsigned int* out = (unsigned int*)(w8 + (size_t)row * D_SZ);
  out[lane] = pack4f8(v0.x * rn, v0.y * rn, v0.z * rn, v0.w * rn);
  out[64 + lane] = pack4f8(v1.x * rn, v1.y * rn, v1.z * rn, v1.w * rn);
}

// ------- kernel 2: normalize embeddings, gather w_y, build fragment-ordered A --
// A8f layout: [frag 0..31][kstep 0..7][slot 0..127][16B].
// slot s holds row (frag*32 + (s&31)), source k-bytes
//   kstep*64 + ((s>>5)&1)*32 + ((s>>6)&1)*16 .. +16  — exactly the 32x32x64
// fp8 operand order the GEMM consumes (matches old LDS staging layout).
// Row 2b = fp8(e_hat[b]); row 2b+1 = fp8 w_hat[label[b]].
__global__ __launch_bounds__(64) void k_prep(const float* __restrict__ e,
                                             const int* __restrict__ labels,
                                             const unsigned char* __restrict__ w8,
                                             unsigned char* __restrict__ A8f,
                                             float4* __restrict__ params) {
  const int b = blockIdx.x;
  const int lane = threadIdx.x;
  const float4* er = (const float4*)(e + (size_t)b * D_SZ);
  float4 v0 = er[lane], v1 = er[64 + lane];
  float ss = v0.x*v0.x + v0.y*v0.y + v0.z*v0.z + v0.w*v0.w
           + v1.x*v1.x + v1.y*v1.y + v1.z*v1.z + v1.w*v1.w;
  #pragma unroll
  for (int o = 32; o; o >>= 1) ss += __shfl_xor(ss, o, 64);
  const float rn = __builtin_amdgcn_rsqf(fmaxf(ss, 1e-24f));
  v0.x *= rn; v0.y *= rn; v0.z *= rn; v0.w *= rn;
  v1.x *= rn; v1.y *= rn; v1.z *= rn; v1.w *= rn;

  const unsigned int ue0 = pack4f8(v0.x, v0.y, v0.z, v0.w);   // elems 4l..
  const unsigned int ue1 = pack4f8(v1.x, v1.y, v1.z, v1.w);   // elems 256+4l..

  const int lab = labels[b];
  const unsigned int* wr = (const unsigned int*)(w8 + (size_t)lab * D_SZ);
  const unsigned int w0 = wr[lane], w1 = wr[64 + lane];

  // fragment-order addresses: elem e0=4*lane (and e1=e0+256 -> same slot, kstep+4)
  const int re = 2 * b;
  const int frag = re >> 5;
  const int rife = re & 31;            // e row within frag; w_y row = rife+1
  const int wk = (4 * lane) & 63;
  const int ks = lane >> 4;            // (4*lane)>>6
  const int sbits = (((wk >> 5) & 1) << 5) | (((wk >> 4) & 1) << 6);
  const int byteo = wk & 15;
  unsigned char* fb = A8f + (size_t)frag * 16384;
  unsigned char* pe = fb + (rife | sbits) * 16 + byteo;
  unsigned char* pw = fb + ((rife + 1) | sbits) * 16 + byteo;
  *(unsigned int*)(pe + ks * 2048) = ue0;
  *(unsigned int*)(pe + (ks + 4) * 2048) = ue1;
  *(unsigned int*)(pw + ks * 2048) = w0;
  *(unsigned int*)(pw + (ks + 4) * 2048) = w1;

  float d = v0.x * fp82f(w0 & 255) + v0.y * fp82f((w0 >> 8) & 255)
          + v0.z * fp82f((w0 >> 16) & 255) + v0.w * fp82f(w0 >> 24)
          + v1.x * fp82f(w1 & 255) + v1.y * fp82f((w1 >> 8) & 255)
          + v1.z * fp82f((w1 >> 16) & 255) + v1.w * fp82f(w1 >> 24);
  #pragma unroll
  for (int o = 32; o; o >>= 1) d += __shfl_xor(d, o, 64);

  if (lane == 0) {
    const float cos_m = 0.877582561890372716f;  // cos(0.5)
    const float sin_m = 0.479425538604203000f;  // sin(0.5)
    float cos_t = fminf(fmaxf(d, -1.0f), 1.0f);
    float sin_t = sqrtf(fmaxf(1.0f - cos_t * cos_t, 0.0f));
    float cos_tm = cos_t * cos_m - sin_t * sin_m;
    float sin_tm = sin_t * cos_m + cos_t * sin_m;
    float inv_st = 1.0f / fmaxf(sin_t, 1e-20f);
    params[b] = make_float4(cos_tm, sin_m * inv_st, sin_tm * inv_st, 0.0f);
  }
}

// -- kernel 3: MX fp8 32x32x64 GEMM; A direct from L2 (fragment-ordered), --
// -- B LDS double-buffered; 8 waves, 1x2 tiles/wave; (512,6) = no spill.  --
__device__ __forceinline__ float termf(float de, float dwy, float4 p, bool kill) {
  float c = fminf(fmaxf(de, -1.0f), 1.0f);
  float s = p.z * dwy - p.y * de;            // (sin_tm*dwy - sin_m*de)/sin_t
  float x = fmaxf(fmaf(-2.0f, s, 2.0f), 1e-20f);
  float t = (c - p.x) * __builtin_amdgcn_rsqf(x);
  float r = __expf(t);
  return kill ? 0.0f : r;
}

__global__ __launch_bounds__(512, 6) void k_gemm(const unsigned char* __restrict__ A8f,
                                                 const unsigned char* __restrict__ W8,
                                                 const float4* __restrict__ params,
                                                 const int* __restrict__ labels,
                                                 float* __restrict__ part) {
  // B-only LDS: frag f (32 rows x 64 k = 2 KB) at f*2048; lane l: lo 16B at
  // f*2048 + l*16, hi at +1024.  Bt buffer = 4 frags = 8 KB.
  __shared__ __align__(32) unsigned char Bt[DEPTH][BN * 64];   // 2 x 8 KB
  __shared__ float ered[64];
  __shared__ float4 pl[64];
  __shared__ int ll[64];

  const int bid = blockIdx.x;
  const int p = (bid & 7) * (NBLK / 8) + (bid >> 3);  // XCD-chunked remap
  const int nt = p >> 3, mt = p & 7;                  // mt fastest within XCD
  const int t = threadIdx.x;
  const int w = t >> 6, l = t & 63;
  const int n0 = nt * BN;
  const int b0 = mt * 64;

  if (t < 64) {
    ered[t] = 0.0f;
    pl[t] = params[b0 + t];
    ll[t] = labels[b0 + t];
  }

  // B staging: thread t stages slot t (16 B).
  // slot t: frag = t>>7, row = frag*32 + (t&31), kpart = ((t>>5)&1)*32 + ((t>>6)&1)*16.
  const int kpart = ((t >> 5) & 1) * 32 + ((t >> 6) & 1) * 16;
  int brow_s = n0 + (t >> 7) * 32 + (t & 31);
  if (brow_s >= C_SZ) brow_s = C_SZ - 1;   // clamp; masked in epilogue
  const int boffs = brow_s * D_SZ + kpart;

  // A: fragment-ordered global, L2-resident. Wave's frag = mt*4 + (w&3).
  const unsigned char* afb =
      A8f + (size_t)(mt * 4 + (w & 3)) * 16384 + l * 16;

  f32x16 accA = {}, accB = {};          // the wave's two 32x32 tiles
  const int fA = w & 3;                  // local m-frag (for epilogue lb)
  const int fB0 = (w >> 2) * 2;          // B frags {fB0, fB0+1}
  const int hi = l >> 5;

#define STAGE(d, ts)                                                        \
  gload_lds16(W8 + (size_t)(boffs + (ts) * 64), (void*)(Bt[d] + t * 16))

  // ---- prologue: stage B tiles 0,1 ----
  STAGE(0, 0);
  STAGE(1, 1);
  asm volatile("s_waitcnt vmcnt(1) lgkmcnt(0)" ::: "memory");  // tile 0 landed
  __builtin_amdgcn_s_barrier();

  // ---- main loop: compute(s); drain; barrier; stage(s+2 into freed buf) ----
  #pragma unroll
  for (int s = 0; s < KSTEPS; ++s) {
    const int d = s & 1;
    // A fragment straight from global (coalesced: 64 lanes x 16B contiguous)
    i32x8 av = ld_a(afb + s * 2048);
    i32x8 bv = ld_frag(Bt[d], fB0, l);
    __builtin_amdgcn_s_setprio(1);
    accA = __builtin_amdgcn_mfma_scale_f32_32x32x64_f8f6f4(
        av, bv, accA, 0, 0, 0, UNITY_SCALE, 0, UNITY_SCALE);
    bv = ld_frag(Bt[d], fB0 + 1, l);     // reuse bv regs to cap live set
    accB = __builtin_amdgcn_mfma_scale_f32_32x32x64_f8f6f4(
        av, bv, accB, 0, 0, 0, UNITY_SCALE, 0, UNITY_SCALE);
    __builtin_amdgcn_s_setprio(0);
    if (s < KSTEPS - 1) {
      asm volatile("s_waitcnt vmcnt(0)" ::: "memory");
      __builtin_amdgcn_s_barrier();   // all waves done reading buf d; tile s+1 ready
      if (s + 2 < KSTEPS)
        STAGE(d, s + 2);
    }
  }
#undef STAGE

  // Epilogue. 32x32 C/D: col = lane&31, row = (r&3)+8*(r>>2)+4*hi.
  // Interleaved A rows: even row = dot_e, odd = dot_wy -> reg pair (r, r+1).
  #pragma unroll
  for (int rp = 0; rp < 8; ++rp) {
    const int r = 2 * rp;
    const int lb = fA * 16 + (rp & 1) + 4 * (rp >> 1) + 2 * hi;
    float4 pp = pl[lb];
    int lab = ll[lb];
    int j0 = n0 + fB0 * 32 + (l & 31);
    int j1 = j0 + 32;
    float s = termf(accA[r], accA[r + 1], pp, (j0 >= C_SZ) || (j0 == lab))
            + termf(accB[r], accB[r + 1], pp, (j1 >= C_SZ) || (j1 == lab));
    #pragma unroll
    for (int o = 1; o < 32; o <<= 1) s += __shfl_xor(s, o, 64);
    if ((l & 31) == 0) atomicAdd(&ered[lb], s);
  }
  __syncthreads();
  if (t < 64) part[(size_t)(b0 + t) * NTILES + nt] = ered[t];
}

// ---------------- kernel 4a: per-batch row sum + log1p ----------------
__global__ __launch_bounds__(256) void k_rowsum(const float* __restrict__ part,
                                                float* __restrict__ rowsum) {
  const int b = blockIdx.x;
  float s = 0.0f;
  for (int i = threadIdx.x; i < NTILES; i += 256) s += part[(size_t)b * NTILES + i];
  #pragma unroll
  for (int o = 32; o; o >>= 1) s += __shfl_xor(s, o, 64);
  __shared__ float red[4];
  if ((threadIdx.x & 63) == 0) red[threadIdx.x >> 6] = s;
  __syncthreads();
  if (threadIdx.x == 0)
    rowsum[b] = log1pf(red[0] + red[1] + red[2] + red[3]);
}

// ---------------- kernel 4b: final mean ----------------
__global__ __launch_bounds__(512) void k_final(const float* __restrict__ rowsum,
                                               float* __restrict__ out) {
  const int b = threadIdx.x;
  float v = rowsum[b];
  __shared__ float red[512];
  red[b] = v;
  __syncthreads();
  #pragma unroll
  for (int o = 256; o; o >>= 1) {
    if (b < o) red[b] += red[b + o];
    __syncthreads();
  }
  if (b == 0) out[0] = red[0] / (float)B_SZ;
}

extern "C" void kernel_launch(void* const* d_in, const int* in_sizes, int n_in,
                              void* d_out, int out_size, void* d_ws, size_t ws_size,
                              hipStream_t stream) {
  const float* emb = (const float*)d_in[0];
  const int* labels = (const int*)d_in[1];
  const float* w = (const float*)d_in[2];

  char* ws = (char*)d_ws;
  unsigned char* w8 = (unsigned char*)ws;                  // 100000*512 B
  size_t off = (size_t)C_SZ * D_SZ;
  unsigned char* A8f = (unsigned char*)(ws + off);         // 32*16384 = 512 KB
  off += (size_t)2 * B_SZ * D_SZ;
  float4* params = (float4*)(ws + off);                    // 512*16 B
  off += (size_t)B_SZ * 16;
  float* part = (float*)(ws + off);                        // 512*782*4 B
  off += (size_t)B_SZ * NTILES * 4;
  float* rowsum = (float*)(ws + off);                      // 512*4 B
  off += (size_t)B_SZ * 4;

  k_norm_w<<<dim3(C_SZ / 4), dim3(256), 0, stream>>>(w, w8);
  k_prep<<<dim3(B_SZ), dim3(64), 0, stream>>>(emb, labels, w8, A8f, params);
  k_gemm<<<dim3(NBLK), dim3(512), 0, stream>>>(A8f, w8, params, labels, part);
  k_rowsum<<<dim3(B_SZ), dim3(256), 0, stream>>>(part, rowsum);
  k_final<<<dim3(1), dim3(512), 0, stream>>>(rowsum, (float*)d_out);
}